// Round 20
// baseline (57.662 us; speedup 1.0000x reference)
//
#include <hip/hip_runtime.h>

#define DIMV 16
#define NSTEP 4095      // 4096 - 1 increments
#define NC 64           // chunks
#define TSTEP 64        // chunk length
#define SIG13 4368      // 16 + 256 + 4096
#define L4 65536        // 16^4

// 16-wide register vector as explicit float4s — never runtime-indexed (rule #20).
struct V16 { float4 a, b, c, d; };

#define EACH(OP) OP(a,x) OP(a,y) OP(a,z) OP(a,w) OP(b,x) OP(b,y) OP(b,z) OP(b,w) \
                 OP(c,x) OP(c,y) OP(c,z) OP(c,w) OP(d,x) OP(d,y) OP(d,z) OP(d,w)

__device__ inline V16 ldv16(const float* p) {
    const float4* q = reinterpret_cast<const float4*>(p);
    V16 v; v.a = q[0]; v.b = q[1]; v.c = q[2]; v.d = q[3]; return v;
}
__device__ inline void stv16(float* p, const V16& v) {
    float4* q = reinterpret_cast<float4*>(p);
    q[0] = v.a; q[1] = v.b; q[2] = v.c; q[3] = v.d;
}
__device__ inline V16 zerov16() {
    V16 v; v.a = v.b = v.c = v.d = make_float4(0.f, 0.f, 0.f, 0.f); return v;
}

// extract float2 (2h, 2h+1) from a V16 via uniform switch (h = blockIdx.y)
__device__ __forceinline__ float2 pick_pair(const V16& v, int h) {
    switch (h) {
        case 0: return make_float2(v.a.x, v.a.y);
        case 1: return make_float2(v.a.z, v.a.w);
        case 2: return make_float2(v.b.x, v.b.y);
        case 3: return make_float2(v.b.z, v.b.w);
        case 4: return make_float2(v.c.x, v.c.y);
        case 5: return make_float2(v.c.z, v.c.w);
        case 6: return make_float2(v.d.x, v.d.y);
        default: return make_float2(v.d.z, v.d.w);
    }
}

// ===== K1: chunk-LOCAL level-4 scan (from zero) — pipelined LDS dx =====
// block (cb, h): chunk cb, j-pair (2h, 2h+1). Staging computes dx rows directly
// into LDS (2 coalesced global reads, 1 sub per slot). Inner loop: double-
// buffered row registers (vA/vB, no rotation movs), 2x unrolled, dj extracted
// from row regs via uniform switch. h==0 blocks also emit the L1-3 chunk sig.
template <bool ATOMIC>
__global__ __launch_bounds__(256, 1) void k_local4(const float* __restrict__ x,
                                                   float* __restrict__ chunk_sig,
                                                   float* __restrict__ dst) {
    __shared__ float sdx[TSTEP * DIMV];        // 4 KB of dx rows
    const int cb = blockIdx.x;   // 0..NC-1
    const int h = blockIdx.y;    // 0..7 : j-pair
    const int t = threadIdx.x;
    const int ia = t >> 4, ib = t & 15;

    const int s0 = cb * TSTEP;
    const int s1 = (s0 + TSTEP < NSTEP) ? (s0 + TSTEP) : NSTEP;
    const int nrow = s1 - s0;                  // 64 (63 for last chunk)

    // stage dx rows: dx4[slot] = x4[slot+4] - x4[slot]  (row = slot>>2)
    {
        const float4* xg = reinterpret_cast<const float4*>(x + (size_t)s0 * DIMV);
        float4* sd4 = reinterpret_cast<float4*>(sdx);
        const int nslot = nrow * (DIMV / 4);   // <= 256
        if (t < nslot) {
            float4 lo = xg[t];
            float4 hi = xg[t + 4];
            sd4[t] = make_float4(hi.x - lo.x, hi.y - lo.y,
                                 hi.z - lo.z, hi.w - lo.w);
        }
    }
    __syncthreads();

    float A1a = 0.f, A2 = 0.f;
    float2 A3p = make_float2(0.f, 0.f);
    V16 A3f = zerov16();                       // full level-3 (used when h==0)
    V16 ac0 = zerov16(), ac1 = zerov16();

    // double-buffered row registers
    V16 vA = ldv16(sdx);       float aA = sdx[ia], bA = sdx[ib];
    V16 vB;                    float aB, bB;

#define STEP(V, Aa, Bb) { \
        float2 dj = pick_pair(V, h); \
        float U2 = fmaf(Bb, fmaf(Aa, 1.f/24.f, A1a * (1.f/6.f)), 0.5f * A2); \
        float V2 = fmaf(Bb, fmaf(Aa, 1.f/6.f, A1a * 0.5f), A2); \
        float h2 = fmaf(Aa, 0.5f, A1a); \
        float u30 = fmaf(dj.x, U2, A3p.x); \
        float u31 = fmaf(dj.y, U2, A3p.y); \
        ac0.a.x = fmaf(u30, V.a.x, ac0.a.x); ac1.a.x = fmaf(u31, V.a.x, ac1.a.x); \
        ac0.a.y = fmaf(u30, V.a.y, ac0.a.y); ac1.a.y = fmaf(u31, V.a.y, ac1.a.y); \
        ac0.a.z = fmaf(u30, V.a.z, ac0.a.z); ac1.a.z = fmaf(u31, V.a.z, ac1.a.z); \
        ac0.a.w = fmaf(u30, V.a.w, ac0.a.w); ac1.a.w = fmaf(u31, V.a.w, ac1.a.w); \
        ac0.b.x = fmaf(u30, V.b.x, ac0.b.x); ac1.b.x = fmaf(u31, V.b.x, ac1.b.x); \
        ac0.b.y = fmaf(u30, V.b.y, ac0.b.y); ac1.b.y = fmaf(u31, V.b.y, ac1.b.y); \
        ac0.b.z = fmaf(u30, V.b.z, ac0.b.z); ac1.b.z = fmaf(u31, V.b.z, ac1.b.z); \
        ac0.b.w = fmaf(u30, V.b.w, ac0.b.w); ac1.b.w = fmaf(u31, V.b.w, ac1.b.w); \
        ac0.c.x = fmaf(u30, V.c.x, ac0.c.x); ac1.c.x = fmaf(u31, V.c.x, ac1.c.x); \
        ac0.c.y = fmaf(u30, V.c.y, ac0.c.y); ac1.c.y = fmaf(u31, V.c.y, ac1.c.y); \
        ac0.c.z = fmaf(u30, V.c.z, ac0.c.z); ac1.c.z = fmaf(u31, V.c.z, ac1.c.z); \
        ac0.c.w = fmaf(u30, V.c.w, ac0.c.w); ac1.c.w = fmaf(u31, V.c.w, ac1.c.w); \
        ac0.d.x = fmaf(u30, V.d.x, ac0.d.x); ac1.d.x = fmaf(u31, V.d.x, ac1.d.x); \
        ac0.d.y = fmaf(u30, V.d.y, ac0.d.y); ac1.d.y = fmaf(u31, V.d.y, ac1.d.y); \
        ac0.d.z = fmaf(u30, V.d.z, ac0.d.z); ac1.d.z = fmaf(u31, V.d.z, ac1.d.z); \
        ac0.d.w = fmaf(u30, V.d.w, ac0.d.w); ac1.d.w = fmaf(u31, V.d.w, ac1.d.w); \
        A3p.x = fmaf(dj.x, V2, A3p.x); \
        A3p.y = fmaf(dj.y, V2, A3p.y); \
        if (h == 0) { \
            A3f.a.x = fmaf(V.a.x, V2, A3f.a.x); A3f.a.y = fmaf(V.a.y, V2, A3f.a.y); \
            A3f.a.z = fmaf(V.a.z, V2, A3f.a.z); A3f.a.w = fmaf(V.a.w, V2, A3f.a.w); \
            A3f.b.x = fmaf(V.b.x, V2, A3f.b.x); A3f.b.y = fmaf(V.b.y, V2, A3f.b.y); \
            A3f.b.z = fmaf(V.b.z, V2, A3f.b.z); A3f.b.w = fmaf(V.b.w, V2, A3f.b.w); \
            A3f.c.x = fmaf(V.c.x, V2, A3f.c.x); A3f.c.y = fmaf(V.c.y, V2, A3f.c.y); \
            A3f.c.z = fmaf(V.c.z, V2, A3f.c.z); A3f.c.w = fmaf(V.c.w, V2, A3f.c.w); \
            A3f.d.x = fmaf(V.d.x, V2, A3f.d.x); A3f.d.y = fmaf(V.d.y, V2, A3f.d.y); \
            A3f.d.z = fmaf(V.d.z, V2, A3f.d.z); A3f.d.w = fmaf(V.d.w, V2, A3f.d.w); \
        } \
        A2 = fmaf(Bb, h2, A2); \
        A1a += Aa; }

    for (int si = 0; si < nrow; si += 2) {
        // prefetch row si+1 into B (clamped)
        {
            int sp = (si + 1 < nrow) ? (si + 1) : si;
            const float* rn = sdx + sp * DIMV;
            vB = ldv16(rn); aB = rn[ia]; bB = rn[ib];
        }
        STEP(vA, aA, bA)
        // prefetch row si+2 into A (clamped)
        {
            int sp = (si + 2 < nrow) ? (si + 2) : si;
            const float* rn = sdx + sp * DIMV;
            vA = ldv16(rn); aA = rn[ia]; bA = rn[ib];
        }
        if (si + 1 < nrow) STEP(vB, aB, bB)
    }
#undef STEP

    if (ATOMIC) {
        float* o = dst + t * 256 + (h * 2) * 16;
#define STA(Q,C,K) atomicAdd(o + (K), ac0.Q.C); atomicAdd(o + 16 + (K), ac1.Q.C);
        STA(a,x,0) STA(a,y,1) STA(a,z,2) STA(a,w,3)
        STA(b,x,4) STA(b,y,5) STA(b,z,6) STA(b,w,7)
        STA(c,x,8) STA(c,y,9) STA(c,z,10) STA(c,w,11)
        STA(d,x,12) STA(d,y,13) STA(d,z,14) STA(d,w,15)
#undef STA
    } else {
        float* o = dst + (size_t)cb * L4 + t * 256 + (h * 2) * 16;
        stv16(o, ac0);
        stv16(o + 16, ac1);
    }

    if (h == 0) {
        float* o = chunk_sig + (size_t)cb * SIG13;
        if (ib == 0) o[ia] = A1a;
        o[16 + t] = A2;
        stv16(o + 272 + t * 16, A3f);
    }
}

// ===== K2: fused cascaded prefix (levels 1,2,3) — R12-proven, unchanged =====
__global__ __launch_bounds__(256, 1) void k_prefixB(const float* __restrict__ chunk_sig,
                                                    float* __restrict__ prefix_sig,
                                                    float* __restrict__ out13) {
    __shared__ float s1s[NC][16];
    __shared__ float p1s[NC][16];
    __shared__ float p2s[NC][16];
    const int a = blockIdx.x;
    const int t = threadIdx.x;

    for (int base = 0; base < NC; base += 16) {
        int c = base + (t >> 4);
        s1s[c][t & 15] = chunk_sig[(size_t)c * SIG13 + (t & 15)];
    }
    __syncthreads();
    if (t < 16) {
        float p = 0.f;
        for (int c = 0; c < NC; ++c) {
            p1s[c][t] = p;
            if (a == 0) prefix_sig[(size_t)c * SIG13 + t] = p;
            p += s1s[c][t];
        }
        if (a == 0) out13[t] = p;
    }
    __syncthreads();
    {
        const int aa = t >> 4, bb = t & 15;
        float pl0 = chunk_sig[0ul * SIG13 + 16 + t];
        float pl1 = chunk_sig[1ul * SIG13 + 16 + t];
        float pl2 = chunk_sig[2ul * SIG13 + 16 + t];
        float pl3 = chunk_sig[3ul * SIG13 + 16 + t];
        float pl4 = chunk_sig[4ul * SIG13 + 16 + t];
        float pl5 = chunk_sig[5ul * SIG13 + 16 + t];
        float pl6 = chunk_sig[6ul * SIG13 + 16 + t];
        float pl7 = chunk_sig[7ul * SIG13 + 16 + t];
        float p = 0.f;
        for (int cb2 = 0; cb2 < NC; cb2 += 8) {
#define STEP2(J) { int c = cb2 + J; \
            if (aa == a) p2s[c][bb] = p; \
            if (a == 0) prefix_sig[(size_t)c * SIG13 + 16 + t] = p; \
            p = fmaf(p1s[c][aa], s1s[c][bb], p + pl##J); \
            int cn = c + 8; \
            if (cn < NC) pl##J = chunk_sig[(size_t)cn * SIG13 + 16 + t]; }
            STEP2(0) STEP2(1) STEP2(2) STEP2(3) STEP2(4) STEP2(5) STEP2(6) STEP2(7)
#undef STEP2
        }
        if (a == 0) out13[16 + t] = p;
    }
    __syncthreads();
    {
        const int c3 = t & 15, k = t >> 4;
        const size_t off3 = 272 + (size_t)a * 256 + t;
#define LD3(J, C) \
        float l3_##J = chunk_sig[(size_t)(C) * SIG13 + off3]; \
        float l2_##J = chunk_sig[(size_t)(C) * SIG13 + 16 + t];
        LD3(0,0) LD3(1,1) LD3(2,2) LD3(3,3) LD3(4,4) LD3(5,5) LD3(6,6) LD3(7,7)
#undef LD3
        float p = 0.f;
        for (int cb2 = 0; cb2 < NC; cb2 += 8) {
#define STEP3(J) { int c = cb2 + J; \
            prefix_sig[(size_t)c * SIG13 + off3] = p; \
            p = p + l3_##J + fmaf(p1s[c][a], l2_##J, p2s[c][k] * s1s[c][c3]); \
            int cn = c + 8; \
            if (cn < NC) { \
                l3_##J = chunk_sig[(size_t)cn * SIG13 + off3]; \
                l2_##J = chunk_sig[(size_t)cn * SIG13 + 16 + t]; } }
            STEP3(0) STEP3(1) STEP3(2) STEP3(3) STEP3(4) STEP3(5) STEP3(6) STEP3(7)
#undef STEP3
        }
        out13[off3] = p;
    }
}

// ===== K3: combine = reduce(partials) + Chen corrections — R19-proven =====
template <bool HAVE_PART>
__global__ __launch_bounds__(256, 1) void k_combine(const float* __restrict__ partials,
                                                    const float* __restrict__ chunk_sig,
                                                    const float* __restrict__ prefix_sig,
                                                    float* __restrict__ out4) {
    const int e = blockIdx.x * 256 + threadIdx.x;  // 0..65535
    const int i_l3 = 272 + (e & 4095);
    const int i_l2 = 16 + (e & 255);
    const int i_l1 = e & 15;
    const int i_p1 = e >> 12;
    const int i_p2 = 16 + (e >> 8);
    const int i_p3 = 272 + (e >> 4);

    float s = 0.f;
#pragma unroll 4
    for (int c = 0; c < NC; ++c) {
        const float* B = chunk_sig + (size_t)c * SIG13;
        const float* P = prefix_sig + (size_t)c * SIG13;
        float corr = fmaf(P[i_p1], B[i_l3],
                     fmaf(P[i_p2], B[i_l2], P[i_p3] * B[i_l1]));
        if (HAVE_PART) s += partials[(size_t)c * L4 + e] + corr;
        else           s += corr;
    }
    if (HAVE_PART) out4[e] = s;
    else           out4[e] += s;   // local-L4 already atomically accumulated
}

extern "C" void kernel_launch(void* const* d_in, const int* in_sizes, int n_in,
                              void* d_out, int out_size, void* d_ws, size_t ws_size,
                              hipStream_t stream) {
    const float* x = (const float*)d_in[0];
    float* out = (float*)d_out;
    float* ws = (float*)d_ws;

    float* chunk_sig = ws;                               // NC * SIG13
    float* prefix_sig = chunk_sig + (size_t)NC * SIG13;  // NC * SIG13
    float* partials = prefix_sig + (size_t)NC * SIG13;   // NC * L4
    const size_t need_bytes =
        (2ull * NC * SIG13 + (size_t)NC * L4) * sizeof(float);

    if (ws_size >= need_bytes) {
        k_local4<false><<<dim3(NC, 8), dim3(256), 0, stream>>>(x, chunk_sig, partials);
        k_prefixB<<<dim3(16), dim3(256), 0, stream>>>(chunk_sig, prefix_sig, out);
        k_combine<true><<<dim3(256), dim3(256), 0, stream>>>(partials, chunk_sig,
                                                             prefix_sig, out + SIG13);
    } else {
        hipMemsetAsync(out + SIG13, 0, (size_t)L4 * sizeof(float), stream);
        k_local4<true><<<dim3(NC, 8), dim3(256), 0, stream>>>(x, chunk_sig, out + SIG13);
        k_prefixB<<<dim3(16), dim3(256), 0, stream>>>(chunk_sig, prefix_sig, out);
        k_combine<false><<<dim3(256), dim3(256), 0, stream>>>(nullptr, chunk_sig,
                                                              prefix_sig, out + SIG13);
    }
}

// Round 21
// 54.338 us; speedup vs baseline: 1.0612x; 1.0612x over previous
//
#include <hip/hip_runtime.h>

#define DIMV 16
#define NSTEP 4095      // 4096 - 1 increments
#define NC 64           // chunks
#define TSTEP 64        // chunk length
#define SIG13 4368      // 16 + 256 + 4096
#define L4 65536        // 16^4

// 16-wide register vector as explicit float4s — never runtime-indexed (rule #20).
struct V16 { float4 a, b, c, d; };

#define EACH(OP) OP(a,x) OP(a,y) OP(a,z) OP(a,w) OP(b,x) OP(b,y) OP(b,z) OP(b,w) \
                 OP(c,x) OP(c,y) OP(c,z) OP(c,w) OP(d,x) OP(d,y) OP(d,z) OP(d,w)

__device__ inline V16 ldv16(const float* p) {
    const float4* q = reinterpret_cast<const float4*>(p);
    V16 v; v.a = q[0]; v.b = q[1]; v.c = q[2]; v.d = q[3]; return v;
}
__device__ inline void stv16(float* p, const V16& v) {
    float4* q = reinterpret_cast<float4*>(p);
    q[0] = v.a; q[1] = v.b; q[2] = v.c; q[3] = v.d;
}
__device__ inline V16 zerov16() {
    V16 v; v.a = v.b = v.c = v.d = make_float4(0.f, 0.f, 0.f, 0.f); return v;
}

// ------------- per-chunk LOCAL signature (levels 1-3) + fused dx, LDS-staged -------------
// (R18-proven, unchanged)
__global__ __launch_bounds__(256, 1) void k_chunk_sig(const float* __restrict__ x,
                                                      float* __restrict__ dx,
                                                      float* __restrict__ chunk_sig) {
    __shared__ float sx[(TSTEP + 1) * DIMV];   // 4.16 KB
    const int cb = blockIdx.x;
    const int t = threadIdx.x;
    const int ia = t >> 4, ib = t & 15;

    const int s0 = cb * TSTEP;
    const int s1 = (s0 + TSTEP < NSTEP) ? (s0 + TSTEP) : NSTEP;
    const int nrow = s1 - s0;                  // dx rows (64; 63 for last chunk)

    {
        const float4* src = reinterpret_cast<const float4*>(x + (size_t)s0 * DIMV);
        float4* sd4 = reinterpret_cast<float4*>(sx);
        const int nslot = (nrow + 1) * (DIMV / 4);   // <= 260
        if (t < nslot) sd4[t] = src[t];
        int slot2 = t + 256;
        if (slot2 < nslot) sd4[slot2] = src[slot2];
    }
    __syncthreads();

    float A1a = 0.f, A2 = 0.f;
    V16 A3 = zerov16();

    V16 xprev = ldv16(sx);
    float xpa = sx[ia], xpb = sx[ib];

    for (int si = 0; si < nrow; ++si) {
        const float* nrowp = sx + (si + 1) * DIMV;
        V16 xcur = ldv16(nrowp);
        float xca = nrowp[ia];
        float xcb = nrowp[ib];

        V16 dxv;
#define SB(Q,C) dxv.Q.C = xcur.Q.C - xprev.Q.C;
        EACH(SB)
#undef SB
        float dxa = xca - xpa;
        float dxb = xcb - xpb;
        stv16(dx + (size_t)(s0 + si) * DIMV, dxv);

        float V2 = fmaf(dxb, fmaf(dxa, 1.f/6.f, 0.5f * A1a), A2);
        float h2 = fmaf(dxa, 0.5f, A1a);
#define CS(Q,C) A3.Q.C = fmaf(dxv.Q.C, V2, A3.Q.C);
        EACH(CS)
#undef CS
        A2 = fmaf(dxb, h2, A2);
        A1a += dxa;

        xprev = xcur; xpa = xca; xpb = xcb;
    }
    float* o = chunk_sig + (size_t)cb * SIG13;
    if (ib == 0) o[ia] = A1a;
    o[16 + t] = A2;
    stv16(o + 272 + t * 16, A3);
}

// ------------- fused cascaded prefix (levels 1,2,3) — R12-proven, unchanged -------------
__global__ __launch_bounds__(256, 1) void k_prefixB(const float* __restrict__ chunk_sig,
                                                    float* __restrict__ prefix_sig,
                                                    float* __restrict__ out13) {
    __shared__ float s1s[NC][16];
    __shared__ float p1s[NC][16];
    __shared__ float p2s[NC][16];
    const int a = blockIdx.x;
    const int t = threadIdx.x;

    for (int base = 0; base < NC; base += 16) {
        int c = base + (t >> 4);
        s1s[c][t & 15] = chunk_sig[(size_t)c * SIG13 + (t & 15)];
    }
    __syncthreads();
    if (t < 16) {
        float p = 0.f;
        for (int c = 0; c < NC; ++c) {
            p1s[c][t] = p;
            if (a == 0) prefix_sig[(size_t)c * SIG13 + t] = p;
            p += s1s[c][t];
        }
        if (a == 0) out13[t] = p;
    }
    __syncthreads();
    {
        const int aa = t >> 4, bb = t & 15;
        float pl0 = chunk_sig[0ul * SIG13 + 16 + t];
        float pl1 = chunk_sig[1ul * SIG13 + 16 + t];
        float pl2 = chunk_sig[2ul * SIG13 + 16 + t];
        float pl3 = chunk_sig[3ul * SIG13 + 16 + t];
        float pl4 = chunk_sig[4ul * SIG13 + 16 + t];
        float pl5 = chunk_sig[5ul * SIG13 + 16 + t];
        float pl6 = chunk_sig[6ul * SIG13 + 16 + t];
        float pl7 = chunk_sig[7ul * SIG13 + 16 + t];
        float p = 0.f;
        for (int cb2 = 0; cb2 < NC; cb2 += 8) {
#define STEP2(J) { int c = cb2 + J; \
            if (aa == a) p2s[c][bb] = p; \
            if (a == 0) prefix_sig[(size_t)c * SIG13 + 16 + t] = p; \
            p = fmaf(p1s[c][aa], s1s[c][bb], p + pl##J); \
            int cn = c + 8; \
            if (cn < NC) pl##J = chunk_sig[(size_t)cn * SIG13 + 16 + t]; }
            STEP2(0) STEP2(1) STEP2(2) STEP2(3) STEP2(4) STEP2(5) STEP2(6) STEP2(7)
#undef STEP2
        }
        if (a == 0) out13[16 + t] = p;
    }
    __syncthreads();
    {
        const int c3 = t & 15, k = t >> 4;
        const size_t off3 = 272 + (size_t)a * 256 + t;
#define LD3(J, C) \
        float l3_##J = chunk_sig[(size_t)(C) * SIG13 + off3]; \
        float l2_##J = chunk_sig[(size_t)(C) * SIG13 + 16 + t];
        LD3(0,0) LD3(1,1) LD3(2,2) LD3(3,3) LD3(4,4) LD3(5,5) LD3(6,6) LD3(7,7)
#undef LD3
        float p = 0.f;
        for (int cb2 = 0; cb2 < NC; cb2 += 8) {
#define STEP3(J) { int c = cb2 + J; \
            prefix_sig[(size_t)c * SIG13 + off3] = p; \
            p = p + l3_##J + fmaf(p1s[c][a], l2_##J, p2s[c][k] * s1s[c][c3]); \
            int cn = c + 8; \
            if (cn < NC) { \
                l3_##J = chunk_sig[(size_t)cn * SIG13 + off3]; \
                l2_##J = chunk_sig[(size_t)cn * SIG13 + 16 + t]; } }
            STEP3(0) STEP3(1) STEP3(2) STEP3(3) STEP3(4) STEP3(5) STEP3(6) STEP3(7)
#undef STEP3
        }
        out13[off3] = p;
    }
}

// ------------- level-4 accumulation: j-pair, UNIFORM (scalar-pipe) row reads -------------
// Single change vs R18: the wave-uniform 64B row vector is read from GLOBAL dx
// with a block-uniform address (expect s_load_dwordx4 -> SGPRs, SMEM pipe),
// relieving the LDS pipe of 4 ds_read_b128 broadcasts per step. LDS keeps only
// the per-lane row[ia]/row[ib] and the cj pair (3 small DS reads/step).
__global__ __launch_bounds__(256, 1) void k_scan4(const float* __restrict__ dx,
                                                  const float* __restrict__ prefix_sig,
                                                  float* __restrict__ dst) {
    __shared__ float sdx[TSTEP * DIMV];   // 4 KB (per-lane indexed reads only)
    const int cb = blockIdx.x;   // 0..NC-1
    const int h = blockIdx.y;    // 0..7 : j-pair
    const int t = threadIdx.x;
    const int ia = t >> 4, ib = t & 15;

    const int s0 = cb * TSTEP;
    const int s1 = (s0 + TSTEP < NSTEP) ? (s0 + TSTEP) : NSTEP;
    const int nrow = s1 - s0;               // 64 (63 for last chunk)

    {
        const float4* src = reinterpret_cast<const float4*>(dx + (size_t)s0 * DIMV);
        float4* sd4 = reinterpret_cast<float4*>(sdx);
        const int nslot = nrow * (DIMV / 4);
#pragma unroll
        for (int k = 0; k < 4; ++k) {
            int slot = t + 256 * k;
            if (slot < nslot) sd4[slot] = src[slot];
        }
    }
    __syncthreads();

    const float* P = prefix_sig + (size_t)cb * SIG13;
    float A1a = P[ia];
    float A2 = P[16 + t];
    float2 A3p = *reinterpret_cast<const float2*>(P + 272 + t * 16 + h * 2);
    V16 ac0 = zerov16(), ac1 = zerov16();

    // uniform global base for the row-vector reads (scalar-load candidate)
    const float4* dxu = reinterpret_cast<const float4*>(dx + (size_t)s0 * DIMV);

#pragma unroll 2
    for (int si = 0; si < nrow; ++si) {
        // wave-uniform address -> SMEM/scalar pipe (s_load_dwordx4), not LDS
        float4 q0 = dxu[si * 4 + 0];
        float4 q1 = dxu[si * 4 + 1];
        float4 q2 = dxu[si * 4 + 2];
        float4 q3 = dxu[si * 4 + 3];
        V16 cur; cur.a = q0; cur.b = q1; cur.c = q2; cur.d = q3;

        const float* row = sdx + si * DIMV;
        float ca = row[ia];                  // per-lane: LDS b32 broadcast-group
        float cbv = row[ib];
        float2 cj = *reinterpret_cast<const float2*>(row + h * 2);  // LDS b64

        float U2 = fmaf(cbv, fmaf(ca, 1.f/24.f, A1a * (1.f/6.f)), 0.5f * A2);
        float V2 = fmaf(cbv, fmaf(ca, 1.f/6.f, A1a * 0.5f), A2);
        float h2 = fmaf(ca, 0.5f, A1a);
        float u30 = fmaf(cj.x, U2, A3p.x);
        float u31 = fmaf(cj.y, U2, A3p.y);
#define AC(Q,C) { ac0.Q.C = fmaf(u30, cur.Q.C, ac0.Q.C); \
                  ac1.Q.C = fmaf(u31, cur.Q.C, ac1.Q.C); }
        EACH(AC)
#undef AC
        A3p.x = fmaf(cj.x, V2, A3p.x);
        A3p.y = fmaf(cj.y, V2, A3p.y);
        A2 = fmaf(cbv, h2, A2);
        A1a += ca;
    }

    float* o = dst + (size_t)cb * L4 + t * 256 + (h * 2) * 16;
    stv16(o, ac0);
    stv16(o + 16, ac1);
}

// ------------- atomic fallback (only if ws too small) -------------
__global__ __launch_bounds__(256, 1) void k_scan4_atomic(const float* __restrict__ dx,
                                                         const float* __restrict__ prefix_sig,
                                                         float* __restrict__ dst) {
    __shared__ float sdx[TSTEP * DIMV];
    const int cb = blockIdx.x;
    const int h = blockIdx.y;
    const int t = threadIdx.x;
    const int ia = t >> 4, ib = t & 15;

    const int s0 = cb * TSTEP;
    const int s1 = (s0 + TSTEP < NSTEP) ? (s0 + TSTEP) : NSTEP;
    const int nrow = s1 - s0;

    {
        const float4* src = reinterpret_cast<const float4*>(dx + (size_t)s0 * DIMV);
        float4* sd4 = reinterpret_cast<float4*>(sdx);
        const int nslot = nrow * (DIMV / 4);
#pragma unroll
        for (int k = 0; k < 4; ++k) {
            int slot = t + 256 * k;
            if (slot < nslot) sd4[slot] = src[slot];
        }
    }
    __syncthreads();

    const float* P = prefix_sig + (size_t)cb * SIG13;
    float A1a = P[ia];
    float A2 = P[16 + t];
    float2 A3p = *reinterpret_cast<const float2*>(P + 272 + t * 16 + h * 2);
    V16 ac0 = zerov16(), ac1 = zerov16();

    const float4* dxu = reinterpret_cast<const float4*>(dx + (size_t)s0 * DIMV);

    for (int si = 0; si < nrow; ++si) {
        float4 q0 = dxu[si * 4 + 0];
        float4 q1 = dxu[si * 4 + 1];
        float4 q2 = dxu[si * 4 + 2];
        float4 q3 = dxu[si * 4 + 3];
        V16 cur; cur.a = q0; cur.b = q1; cur.c = q2; cur.d = q3;

        const float* row = sdx + si * DIMV;
        float ca = row[ia];
        float cbv = row[ib];
        float2 cj = *reinterpret_cast<const float2*>(row + h * 2);

        float U2 = fmaf(cbv, fmaf(ca, 1.f/24.f, A1a * (1.f/6.f)), 0.5f * A2);
        float V2 = fmaf(cbv, fmaf(ca, 1.f/6.f, A1a * 0.5f), A2);
        float h2 = fmaf(ca, 0.5f, A1a);
        float u30 = fmaf(cj.x, U2, A3p.x);
        float u31 = fmaf(cj.y, U2, A3p.y);
#define AC(Q,C) { ac0.Q.C = fmaf(u30, cur.Q.C, ac0.Q.C); \
                  ac1.Q.C = fmaf(u31, cur.Q.C, ac1.Q.C); }
        EACH(AC)
#undef AC
        A3p.x = fmaf(cj.x, V2, A3p.x);
        A3p.y = fmaf(cj.y, V2, A3p.y);
        A2 = fmaf(cbv, h2, A2);
        A1a += ca;
    }

    float* o = dst + t * 256 + (h * 2) * 16;
#define STA(Q,C,K) atomicAdd(o + (K), ac0.Q.C); atomicAdd(o + 16 + (K), ac1.Q.C);
    STA(a,x,0) STA(a,y,1) STA(a,z,2) STA(a,w,3)
    STA(b,x,4) STA(b,y,5) STA(b,z,6) STA(b,w,7)
    STA(c,x,8) STA(c,y,9) STA(c,z,10) STA(c,w,11)
    STA(d,x,12) STA(d,y,13) STA(d,z,14) STA(d,w,15)
#undef STA
}

// ------------- sum per-chunk level-4 partials (float2, 128 blocks) -------------
__global__ __launch_bounds__(256) void k_reduce4(const float* __restrict__ partials,
                                                 float* __restrict__ out4) {
    const int i2 = blockIdx.x * 256 + threadIdx.x;  // 0..32767 float2 slots
    const float2* p2 = reinterpret_cast<const float2*>(partials);
    float2 s = make_float2(0.f, 0.f);
#pragma unroll 8
    for (int c = 0; c < NC; ++c) {
        float2 v = p2[(size_t)c * (L4 / 2) + i2];
        s.x += v.x; s.y += v.y;
    }
    reinterpret_cast<float2*>(out4)[i2] = s;
}

extern "C" void kernel_launch(void* const* d_in, const int* in_sizes, int n_in,
                              void* d_out, int out_size, void* d_ws, size_t ws_size,
                              hipStream_t stream) {
    const float* x = (const float*)d_in[0];
    float* out = (float*)d_out;
    float* ws = (float*)d_ws;

    float* dx = ws;                                     // 65536 floats
    float* chunk_sig = ws + 65536;                      // NC * SIG13
    float* prefix_sig = chunk_sig + (size_t)NC * SIG13; // NC * SIG13
    float* partials = prefix_sig + (size_t)NC * SIG13;  // NC * L4
    const size_t need_bytes =
        ((size_t)65536 + 2ull * NC * SIG13 + (size_t)NC * L4) * sizeof(float);

    k_chunk_sig<<<dim3(NC), dim3(256), 0, stream>>>(x, dx, chunk_sig);
    k_prefixB<<<dim3(16), dim3(256), 0, stream>>>(chunk_sig, prefix_sig, out);

    if (ws_size >= need_bytes) {
        k_scan4<<<dim3(NC, 8), dim3(256), 0, stream>>>(dx, prefix_sig, partials);
        k_reduce4<<<dim3(128), dim3(256), 0, stream>>>(partials, out + SIG13);
    } else {
        hipMemsetAsync(out + SIG13, 0, (size_t)L4 * sizeof(float), stream);
        k_scan4_atomic<<<dim3(NC, 8), dim3(256), 0, stream>>>(dx, prefix_sig,
                                                              out + SIG13);
    }
}

// Round 22
// 43.475 us; speedup vs baseline: 1.3263x; 1.2499x over previous
//
#include <hip/hip_runtime.h>

#define DIMV 16
#define NSTEP 4095      // 4096 - 1 increments
#define NC 64           // chunks
#define TSTEP 64        // chunk length
#define SIG13 4368      // 16 + 256 + 4096
#define L4 65536        // 16^4

// 16-wide register vector as explicit float4s — never runtime-indexed (rule #20).
struct V16 { float4 a, b, c, d; };

#define EACH(OP) OP(a,x) OP(a,y) OP(a,z) OP(a,w) OP(b,x) OP(b,y) OP(b,z) OP(b,w) \
                 OP(c,x) OP(c,y) OP(c,z) OP(c,w) OP(d,x) OP(d,y) OP(d,z) OP(d,w)

__device__ inline V16 ldv16(const float* p) {
    const float4* q = reinterpret_cast<const float4*>(p);
    V16 v; v.a = q[0]; v.b = q[1]; v.c = q[2]; v.d = q[3]; return v;
}
__device__ inline void stv16(float* p, const V16& v) {
    float4* q = reinterpret_cast<float4*>(p);
    q[0] = v.a; q[1] = v.b; q[2] = v.c; q[3] = v.d;
}
__device__ inline V16 zerov16() {
    V16 v; v.a = v.b = v.c = v.d = make_float4(0.f, 0.f, 0.f, 0.f); return v;
}

// ===== K1: chunk-LOCAL level-4 scan (from zero; no dependencies) =====
// (R19-proven verbatim.) block (cb, h): chunk cb, j-pair (2h, 2h+1). Stages the
// x-chunk into LDS, computes dx in registers, runs the 64-step local recurrence.
// h==0 blocks also write the levels-1..3 chunk signature.
template <bool ATOMIC>
__global__ __launch_bounds__(256, 1) void k_local4(const float* __restrict__ x,
                                                   float* __restrict__ chunk_sig,
                                                   float* __restrict__ dst) {
    __shared__ float sx[(TSTEP + 1) * DIMV];   // 4.16 KB
    const int cb = blockIdx.x;   // 0..NC-1
    const int h = blockIdx.y;    // 0..7 : j-pair
    const int t = threadIdx.x;
    const int ia = t >> 4, ib = t & 15;

    const int s0 = cb * TSTEP;
    const int s1 = (s0 + TSTEP < NSTEP) ? (s0 + TSTEP) : NSTEP;
    const int nrow = s1 - s0;                  // 64 (63 for last chunk)

    {
        const float4* src = reinterpret_cast<const float4*>(x + (size_t)s0 * DIMV);
        float4* sd4 = reinterpret_cast<float4*>(sx);
        const int nslot = (nrow + 1) * (DIMV / 4);   // <= 260
        if (t < nslot) sd4[t] = src[t];
        int slot2 = t + 256;
        if (slot2 < nslot) sd4[slot2] = src[slot2];
    }
    __syncthreads();

    float A1a = 0.f, A2 = 0.f;
    float2 A3p = make_float2(0.f, 0.f);
    V16 A3f = zerov16();                       // full level-3 (used when h==0)
    V16 ac0 = zerov16(), ac1 = zerov16();

    V16 xprev = ldv16(sx);
    float xpa = sx[ia], xpb = sx[ib];
    float2 xpj = *reinterpret_cast<const float2*>(sx + 2 * h);

    for (int si = 0; si < nrow; ++si) {
        const float* nr = sx + (si + 1) * DIMV;
        V16 xc = ldv16(nr);                    // wave-uniform -> LDS broadcast
        float xca = nr[ia];
        float xcb = nr[ib];
        float2 xcj = *reinterpret_cast<const float2*>(nr + 2 * h);

        V16 dxv;
#define SB(Q,C) dxv.Q.C = xc.Q.C - xprev.Q.C;
        EACH(SB)
#undef SB
        float dxa = xca - xpa;
        float dxb = xcb - xpb;
        float2 dj = make_float2(xcj.x - xpj.x, xcj.y - xpj.y);

        float U2 = fmaf(dxb, fmaf(dxa, 1.f/24.f, A1a * (1.f/6.f)), 0.5f * A2);
        float V2 = fmaf(dxb, fmaf(dxa, 1.f/6.f, A1a * 0.5f), A2);
        float h2 = fmaf(dxa, 0.5f, A1a);
        float u30 = fmaf(dj.x, U2, A3p.x);
        float u31 = fmaf(dj.y, U2, A3p.y);
#define AC(Q,C) { ac0.Q.C = fmaf(u30, dxv.Q.C, ac0.Q.C); \
                  ac1.Q.C = fmaf(u31, dxv.Q.C, ac1.Q.C); }
        EACH(AC)
#undef AC
        A3p.x = fmaf(dj.x, V2, A3p.x);
        A3p.y = fmaf(dj.y, V2, A3p.y);
        if (h == 0) {
#define CS(Q,C) A3f.Q.C = fmaf(dxv.Q.C, V2, A3f.Q.C);
            EACH(CS)
#undef CS
        }
        A2 = fmaf(dxb, h2, A2);
        A1a += dxa;

        xprev = xc; xpa = xca; xpb = xcb; xpj = xcj;
    }

    if (ATOMIC) {
        float* o = dst + t * 256 + (h * 2) * 16;
#define STA(Q,C,K) atomicAdd(o + (K), ac0.Q.C); atomicAdd(o + 16 + (K), ac1.Q.C);
        STA(a,x,0) STA(a,y,1) STA(a,z,2) STA(a,w,3)
        STA(b,x,4) STA(b,y,5) STA(b,z,6) STA(b,w,7)
        STA(c,x,8) STA(c,y,9) STA(c,z,10) STA(c,w,11)
        STA(d,x,12) STA(d,y,13) STA(d,z,14) STA(d,w,15)
#undef STA
    } else {
        float* o = dst + (size_t)cb * L4 + t * 256 + (h * 2) * 16;
        stv16(o, ac0);
        stv16(o + 16, ac1);
    }

    if (h == 0) {
        float* o = chunk_sig + (size_t)cb * SIG13;
        if (ib == 0) o[ia] = A1a;
        o[16 + t] = A2;
        stv16(o + 272 + t * 16, A3f);
    }
}

// ===== K2: fused prefix-cascade + correction + reduce (single loop) =====
// block (a,b) = (blockIdx.x, blockIdx.y); thread t = j*16+d. Runs the 64-chunk
// Chen cascade inline in registers (P1[a], P2[ab], P3[abj] — exact prefixB
// recurrence) while accumulating out4[e] = sum_c{ part + P1*L3[bjd] +
// P2*L2[jd] + P3*L1[d] }. Writes levels-1..3 finals. prefix_sig never exists.
template <bool HAVE_PART>
__global__ __launch_bounds__(256, 1) void k_fuse(const float* __restrict__ partials,
                                                 const float* __restrict__ chunk_sig,
                                                 float* __restrict__ out13,
                                                 float* __restrict__ out4) {
    const int a = blockIdx.x;      // 0..15
    const int b = blockIdx.y;      // 0..15
    const int t = threadIdx.x;     // j*16 + d
    const int j = t >> 4, d = t & 15;
    const int e = a * 4096 + b * 256 + t;

    float P1 = 0.f, P2 = 0.f, P3 = 0.f, acc = 0.f;

    // 4-deep statically-named prefetch (rule #20)
#define DECL(J) float s1a_##J, s1b_##J, s1j_##J, l2ab_##J, l2bj_##J, l2jd_##J, \
                      l3abj_##J, l3bjd_##J, l1d_##J, pt_##J;
    DECL(0) DECL(1) DECL(2) DECL(3)
#undef DECL
#define PLOAD(J, C) { int cc = (C) < NC ? (C) : NC - 1; \
    const float* B = chunk_sig + (size_t)cc * SIG13; \
    s1a_##J = B[a]; s1b_##J = B[b]; s1j_##J = B[j]; l1d_##J = B[d]; \
    l2ab_##J = B[16 + a * 16 + b]; \
    l2bj_##J = B[16 + b * 16 + j]; \
    l2jd_##J = B[16 + t]; \
    l3abj_##J = B[272 + a * 256 + b * 16 + j]; \
    l3bjd_##J = B[272 + b * 256 + t]; \
    pt_##J = HAVE_PART ? partials[(size_t)cc * L4 + e] : 0.f; }
    PLOAD(0, 0) PLOAD(1, 1) PLOAD(2, 2) PLOAD(3, 3)

    for (int c0 = 0; c0 < NC; c0 += 4) {
#define PSTEP(J) { int c = c0 + J; \
        acc += pt_##J + fmaf(P1, l3bjd_##J, fmaf(P2, l2jd_##J, P3 * l1d_##J)); \
        P3 += l3abj_##J + fmaf(P1, l2bj_##J, P2 * s1j_##J); \
        P2 += l2ab_##J + P1 * s1b_##J; \
        P1 += s1a_##J; \
        PLOAD(J, c + 4) }
        PSTEP(0) PSTEP(1) PSTEP(2) PSTEP(3)
#undef PSTEP
    }
#undef PLOAD

    // levels 1-3 finals (inclusive prefixes)
    if (b == 0 && t == 0) out13[a] = P1;
    if (t == 0) out13[16 + a * 16 + b] = P2;
    if (d == 0) out13[272 + a * 256 + b * 16 + j] = P3;

    if (HAVE_PART) out4[e] = acc;
    else           out4[e] += acc;   // local-L4 already atomically accumulated
}

extern "C" void kernel_launch(void* const* d_in, const int* in_sizes, int n_in,
                              void* d_out, int out_size, void* d_ws, size_t ws_size,
                              hipStream_t stream) {
    const float* x = (const float*)d_in[0];
    float* out = (float*)d_out;
    float* ws = (float*)d_ws;

    float* chunk_sig = ws;                               // NC * SIG13
    float* partials = chunk_sig + (size_t)NC * SIG13;    // NC * L4
    const size_t need_bytes =
        ((size_t)NC * SIG13 + (size_t)NC * L4) * sizeof(float);

    if (ws_size >= need_bytes) {
        k_local4<false><<<dim3(NC, 8), dim3(256), 0, stream>>>(x, chunk_sig, partials);
        k_fuse<true><<<dim3(16, 16), dim3(256), 0, stream>>>(partials, chunk_sig,
                                                             out, out + SIG13);
    } else {
        hipMemsetAsync(out + SIG13, 0, (size_t)L4 * sizeof(float), stream);
        k_local4<true><<<dim3(NC, 8), dim3(256), 0, stream>>>(x, chunk_sig, out + SIG13);
        k_fuse<false><<<dim3(16, 16), dim3(256), 0, stream>>>(nullptr, chunk_sig,
                                                              out, out + SIG13);
    }
}